// Round 1
// baseline (1439.171 us; speedup 1.0000x reference)
//
#include <hip/hip_runtime.h>
#include <hip/hip_fp16.h>

typedef _Float16 half8  __attribute__((ext_vector_type(8)));
typedef _Float16 half4v __attribute__((ext_vector_type(4)));
typedef float    f32x4  __attribute__((ext_vector_type(4)));

#define MFMA16(af, bf, cf) __builtin_amdgcn_mfma_f32_16x16x32_f16((af), (bf), (cf), 0, 0, 0)

// ---------------- packing geometry (all sizes in halves) ----------------
#define WL_PACK_H   (32*8*512)   // 131072 per layer: [nt 0..31][kt 0..7][lane][8]
#define WIN_PACK_H  (8*3*512)    // 12288:            [nt 0..7][kt 0..2][lane][8]
#define WOUT_PACK_H (2*4*512)    // 4096:             [nt 0..1][kt 0..3][lane][8]

#define WS_WL0  0
#define WS_WL1  (WS_WL0 + WL_PACK_H)
#define WS_WIN  (WS_WL1 + WL_PACK_H)
#define WS_WOUT (WS_WIN + WIN_PACK_H)

// ---------------- LDS layout (halves) ----------------
#define PITCH_A  392     // 384 cols (a|h0|h1) + 8 pad
#define PITCH_A0 104     // 96 cols (x|acc) + 8 pad
#define L_WL1  0                               // Wl1 kt0..3: [(nt*4+kt)*512 + lane*8]
#define L_WOUT (L_WL1 + 32*4*512)              // 65536
#define L_ABIG (L_WOUT + WOUT_PACK_H)          // 69632
#define L_A0   (L_ABIG + 16*PITCH_A)           // 75904
#define L_TOT  (L_A0 + 16*PITCH_A0)            // 77568 halves = 155136 B

__device__ __forceinline__ float sigm(float x) {
    return __builtin_amdgcn_rcpf(1.0f + __builtin_amdgcn_exp2f(-1.442695041f * x));
}
__device__ __forceinline__ float tanh_(float x) {
    // tanh(x) = 1 - 2/(e^{2x}+1); exp2 overflow -> inf -> correct +/-1 saturation
    return 1.0f - 2.0f * __builtin_amdgcn_rcpf(__builtin_amdgcn_exp2f(2.885390082f * x) + 1.0f);
}

// Pack one LSTM layer's [k;rk] (256x512 f32) into fp16 MFMA B-fragments.
// Column permutation: nt = w*8 + g*2 + hh  ->  src col = g*128 + w*32 + hh*16 + (lane&15)
__global__ void pack_layer_k(const float* __restrict__ kk, const float* __restrict__ rk,
                             _Float16* __restrict__ dst)
{
    int idx  = blockIdx.x * 256 + threadIdx.x;   // 0..131071
    int j    = idx & 7;
    int lane = (idx >> 3) & 63;
    int fk   = idx >> 9;                          // nt*8 + kt
    int kt   = fk & 7;
    int nt   = fk >> 3;
    int w = nt >> 3, ln = nt & 7, g = ln >> 1, hh = ln & 1;
    int col = g*128 + w*32 + hh*16 + (lane & 15);
    int row = kt*32 + (lane >> 4)*8 + j;
    float v = (row < 128) ? kk[row*512 + col] : rk[(row - 128)*512 + col];
    dst[idx] = (_Float16)v;
}

__global__ void pack_small_k(const float* __restrict__ W_in, const float* __restrict__ W_out,
                             _Float16* __restrict__ dwin, _Float16* __restrict__ dwout)
{
    int idx = blockIdx.x * 256 + threadIdx.x;    // 0..12287
    {
        int j = idx & 7, lane = (idx >> 3) & 63, fk = idx >> 9;  // nt*3 + kt
        int kt = fk % 3, nt = fk / 3;
        int col = nt*16 + (lane & 15);
        int row = kt*32 + (lane >> 4)*8 + j;
        dwin[idx] = (_Float16)W_in[row*128 + col];
    }
    if (idx < WOUT_PACK_H) {
        int j = idx & 7, lane = (idx >> 3) & 63, fk = idx >> 9;  // nt*4 + kt
        int kt = fk & 3, nt = fk >> 2;
        int col = nt*16 + (lane & 15);
        int row = kt*32 + (lane >> 4)*8 + j;
        dwout[idx] = (_Float16)W_out[row*32 + col];
    }
}

__global__ __launch_bounds__(256, 1)
void acclstm_main(const float* __restrict__ xin,
                  const _Float16* __restrict__ wl0p, const _Float16* __restrict__ wl1p,
                  const _Float16* __restrict__ winp, const _Float16* __restrict__ woutp,
                  const float* __restrict__ bin, const float* __restrict__ bb0,
                  const float* __restrict__ bb1, const float* __restrict__ bout,
                  float* __restrict__ out)
{
    __shared__ __align__(16) _Float16 lds[L_TOT];
    const int tid  = threadIdx.x;
    const int w    = tid >> 6;        // wave 0..3
    const int lane = tid & 63;
    const int l15  = lane & 15;
    const int lg   = lane >> 4;
    const int b0   = blockIdx.x << 4; // 16 batch rows per block

    // ---- prologue: fill LDS (Wl1 kt0..3, W_out, zero activation tile) ----
    for (int i = tid; i < 8192; i += 256) {
        int h   = i << 3;
        int nt  = h >> 11;           // 2048 halves per nt in dst
        int rem = h & 2047;          // kt*512 + lane*8 + j  (kt<4)
        *reinterpret_cast<uint4*>(&lds[L_WL1 + h]) =
            *reinterpret_cast<const uint4*>(&wl1p[nt*4096 + rem]);
    }
    for (int i = tid; i < 512; i += 256)
        *reinterpret_cast<uint4*>(&lds[L_WOUT + (i << 3)]) =
            *reinterpret_cast<const uint4*>(&woutp[i << 3]);
    {
        uint4 z; z.x = z.y = z.z = z.w = 0u;
        for (int i = tid; i < 784; i += 256)
            *reinterpret_cast<uint4*>(&lds[L_ABIG + (i << 3)]) = z;
    }

    // ---- persistent register weight fragments ----
    half8 wl0r[4][2][8];   // [gate][hh][kt]  layer0 full
    half8 wl1r[4][2][4];   // [gate][hh][kt-4] layer1 high-K (recurrent part)
    #pragma unroll
    for (int g = 0; g < 4; ++g)
      #pragma unroll
      for (int hh = 0; hh < 2; ++hh) {
        const int nt = w*8 + g*2 + hh;
        #pragma unroll
        for (int kt = 0; kt < 8; ++kt)
            wl0r[g][hh][kt] = *reinterpret_cast<const half8*>(&wl0p[(nt*8 + kt)*512 + lane*8]);
        #pragma unroll
        for (int kt = 0; kt < 4; ++kt)
            wl1r[g][hh][kt] = *reinterpret_cast<const half8*>(&wl1p[(nt*8 + 4 + kt)*512 + lane*8]);
      }
    half8 winr[2][3];
    #pragma unroll
    for (int n = 0; n < 2; ++n)
      #pragma unroll
      for (int kt = 0; kt < 3; ++kt)
          winr[n][kt] = *reinterpret_cast<const half8*>(&winp[((w*2 + n)*3 + kt)*512 + lane*8]);

    float bb0v[4][2], bb1v[4][2];
    #pragma unroll
    for (int g = 0; g < 4; ++g)
      #pragma unroll
      for (int hh = 0; hh < 2; ++hh) {
          const int col = g*128 + w*32 + hh*16 + l15;
          bb0v[g][hh] = bb0[col];
          bb1v[g][hh] = bb1[col];
      }
    float binv0 = bin[(w*2 + 0)*16 + l15];
    float binv1 = bin[(w*2 + 1)*16 + l15];
    float boutv = (w < 2) ? bout[w*16 + l15] : 0.0f;

    f32x4 c0[2], c1[2], accv;
    #pragma unroll
    for (int hh = 0; hh < 2; ++hh) {
        c0[hh] = (f32x4){0.f,0.f,0.f,0.f};
        c1[hh] = (f32x4){0.f,0.f,0.f,0.f};
    }
    accv = (f32x4){0.f,0.f,0.f,0.f};

    const int xrow = tid >> 4, xc4 = (tid & 15) << 2;
    float4 xr = *reinterpret_cast<const float4*>(&xin[(size_t)(b0 + xrow)*16384 + xc4]);

    __syncthreads();

    #pragma unroll 1
    for (int t = 0; t < 256; ++t) {
        // ---- phase A: stage A0 = [x_t | acc] as fp16; prefetch x_{t+1} ----
        {
            half4v xh = { (_Float16)xr.x, (_Float16)xr.y, (_Float16)xr.z, (_Float16)xr.w };
            *reinterpret_cast<half4v*>(&lds[L_A0 + xrow*PITCH_A0 + xc4]) = xh;
        }
        if (w < 2) {
            #pragma unroll
            for (int r = 0; r < 4; ++r)
                lds[L_A0 + (lg*4 + r)*PITCH_A0 + 64 + w*16 + l15] = (_Float16)accv[r];
        }
        {
            const int tn = (t < 255) ? (t + 1) : t;
            xr = *reinterpret_cast<const float4*>(&xin[(size_t)(b0 + xrow)*16384 + tn*64 + xc4]);
        }
        __syncthreads();  // B1: A0 ready

        // ---- GEMM1: a = A0 @ W_in + b_in -> Abig cols [32w, 32w+32) ----
        f32x4 aa0 = {0.f,0.f,0.f,0.f}, aa1 = {0.f,0.f,0.f,0.f};
        #pragma unroll
        for (int kt = 0; kt < 3; ++kt) {
            half8 af = *reinterpret_cast<const half8*>(&lds[L_A0 + l15*PITCH_A0 + kt*32 + lg*8]);
            aa0 = MFMA16(af, winr[0][kt], aa0);
            aa1 = MFMA16(af, winr[1][kt], aa1);
        }
        #pragma unroll
        for (int r = 0; r < 4; ++r) {
            lds[L_ABIG + (lg*4 + r)*PITCH_A + w*32 + l15]      = (_Float16)(aa0[r] + binv0);
            lds[L_ABIG + (lg*4 + r)*PITCH_A + w*32 + 16 + l15] = (_Float16)(aa1[r] + binv1);
        }
        __syncthreads();  // B2: a ready

        // ---- LSTM layer 0: z = [a | h0_prev] @ Wl0 (all frags in regs) ----
        float h0n[2][4];
        #pragma unroll
        for (int hh = 0; hh < 2; ++hh) {
            f32x4 z0 = {0.f,0.f,0.f,0.f}, z1 = {0.f,0.f,0.f,0.f};
            f32x4 z2 = {0.f,0.f,0.f,0.f}, z3 = {0.f,0.f,0.f,0.f};
            #pragma unroll
            for (int kt = 0; kt < 8; ++kt) {
                half8 af = *reinterpret_cast<const half8*>(&lds[L_ABIG + l15*PITCH_A + kt*32 + lg*8]);
                z0 = MFMA16(af, wl0r[0][hh][kt], z0);
                z1 = MFMA16(af, wl0r[1][hh][kt], z1);
                z2 = MFMA16(af, wl0r[2][hh][kt], z2);
                z3 = MFMA16(af, wl0r[3][hh][kt], z3);
            }
            #pragma unroll
            for (int r = 0; r < 4; ++r) {
                float iv = sigm (z0[r] + bb0v[0][hh]);
                float fv = sigm (z1[r] + bb0v[1][hh]);
                float gv = tanh_(z2[r] + bb0v[2][hh]);
                float ov = sigm (z3[r] + bb0v[3][hh]);
                float cn = fv * c0[hh][r] + iv * gv;
                c0[hh][r] = cn;
                h0n[hh][r] = ov * tanh_(cn);
            }
        }
        __syncthreads();  // B3: everyone done reading a & h0_prev
        #pragma unroll
        for (int hh = 0; hh < 2; ++hh)
          #pragma unroll
          for (int r = 0; r < 4; ++r)
            lds[L_ABIG + (lg*4 + r)*PITCH_A + 128 + w*32 + hh*16 + l15] = (_Float16)h0n[hh][r];
        __syncthreads();  // B4: h0_new visible

        // ---- LSTM layer 1: z = [h0 | h1_prev] @ Wl1 (kt0..3 LDS, kt4..7 regs) ----
        float h1n[2][4];
        #pragma unroll
        for (int hh = 0; hh < 2; ++hh) {
            f32x4 z0 = {0.f,0.f,0.f,0.f}, z1 = {0.f,0.f,0.f,0.f};
            f32x4 z2 = {0.f,0.f,0.f,0.f}, z3 = {0.f,0.f,0.f,0.f};
            #pragma unroll
            for (int kt = 0; kt < 4; ++kt) {
                half8 af = *reinterpret_cast<const half8*>(&lds[L_ABIG + l15*PITCH_A + 128 + kt*32 + lg*8]);
                z0 = MFMA16(af, *reinterpret_cast<const half8*>(&lds[L_WL1 + ((w*8 + 0 + hh)*4 + kt)*512 + lane*8]), z0);
                z1 = MFMA16(af, *reinterpret_cast<const half8*>(&lds[L_WL1 + ((w*8 + 2 + hh)*4 + kt)*512 + lane*8]), z1);
                z2 = MFMA16(af, *reinterpret_cast<const half8*>(&lds[L_WL1 + ((w*8 + 4 + hh)*4 + kt)*512 + lane*8]), z2);
                z3 = MFMA16(af, *reinterpret_cast<const half8*>(&lds[L_WL1 + ((w*8 + 6 + hh)*4 + kt)*512 + lane*8]), z3);
            }
            #pragma unroll
            for (int kt = 4; kt < 8; ++kt) {
                half8 af = *reinterpret_cast<const half8*>(&lds[L_ABIG + l15*PITCH_A + 128 + kt*32 + lg*8]);
                z0 = MFMA16(af, wl1r[0][hh][kt-4], z0);
                z1 = MFMA16(af, wl1r[1][hh][kt-4], z1);
                z2 = MFMA16(af, wl1r[2][hh][kt-4], z2);
                z3 = MFMA16(af, wl1r[3][hh][kt-4], z3);
            }
            #pragma unroll
            for (int r = 0; r < 4; ++r) {
                float iv = sigm (z0[r] + bb1v[0][hh]);
                float fv = sigm (z1[r] + bb1v[1][hh]);
                float gv = tanh_(z2[r] + bb1v[2][hh]);
                float ov = sigm (z3[r] + bb1v[3][hh]);
                float cn = fv * c1[hh][r] + iv * gv;
                c1[hh][r] = cn;
                h1n[hh][r] = ov * tanh_(cn);
            }
        }
        __syncthreads();  // B5: everyone done reading h0 & h1_prev
        #pragma unroll
        for (int hh = 0; hh < 2; ++hh)
          #pragma unroll
          for (int r = 0; r < 4; ++r)
            lds[L_ABIG + (lg*4 + r)*PITCH_A + 256 + w*32 + hh*16 + l15] = (_Float16)h1n[hh][r];
        __syncthreads();  // B6: h1_new visible

        // ---- GEMM4: res = h1 @ W_out + b_out; out store; acc += res (waves 0,1) ----
        if (w < 2) {
            f32x4 rr = {0.f,0.f,0.f,0.f};
            #pragma unroll
            for (int kt = 0; kt < 4; ++kt) {
                half8 af = *reinterpret_cast<const half8*>(&lds[L_ABIG + l15*PITCH_A + 256 + kt*32 + lg*8]);
                half8 wf = *reinterpret_cast<const half8*>(&lds[L_WOUT + (w*4 + kt)*512 + lane*8]);
                rr = MFMA16(af, wf, rr);
            }
            #pragma unroll
            for (int r = 0; r < 4; ++r) {
                float res = rr[r] + boutv;
                out[(size_t)(b0 + lg*4 + r)*8192 + t*32 + w*16 + l15] = res;
                accv[r] += res;
            }
        }
        // B1 of the next iteration orders GEMM4 reads vs next a-writes.
    }
}

extern "C" void kernel_launch(void* const* d_in, const int* in_sizes, int n_in,
                              void* d_out, int out_size, void* d_ws, size_t ws_size,
                              hipStream_t stream) {
    (void)in_sizes; (void)n_in; (void)out_size; (void)ws_size;
    const float* x     = (const float*)d_in[0];
    const float* W_in  = (const float*)d_in[1];
    const float* b_in  = (const float*)d_in[2];
    const float* k0    = (const float*)d_in[3];
    const float* rk0   = (const float*)d_in[4];
    const float* bb0   = (const float*)d_in[5];
    const float* k1    = (const float*)d_in[6];
    const float* rk1   = (const float*)d_in[7];
    const float* bb1   = (const float*)d_in[8];
    const float* W_out = (const float*)d_in[9];
    const float* b_out = (const float*)d_in[10];
    float* out = (float*)d_out;

    _Float16* ws    = (_Float16*)d_ws;
    _Float16* wl0p  = ws + WS_WL0;
    _Float16* wl1p  = ws + WS_WL1;
    _Float16* winp  = ws + WS_WIN;
    _Float16* woutp = ws + WS_WOUT;

    pack_layer_k<<<512, 256, 0, stream>>>(k0, rk0, wl0p);
    pack_layer_k<<<512, 256, 0, stream>>>(k1, rk1, wl1p);
    pack_small_k<<<48, 256, 0, stream>>>(W_in, W_out, winp, woutp);
    acclstm_main<<<256, 256, 0, stream>>>(x, wl0p, wl1p, winp, woutp,
                                          b_in, bb0, bb1, b_out, out);
}

// Round 2
// 1429.598 us; speedup vs baseline: 1.0067x; 1.0067x over previous
//
#include <hip/hip_runtime.h>
#include <hip/hip_fp16.h>

typedef _Float16 half8  __attribute__((ext_vector_type(8)));
typedef _Float16 half2v __attribute__((ext_vector_type(2)));
typedef float    f32x4  __attribute__((ext_vector_type(4)));

#define MFMA16(af, bf, cf) __builtin_amdgcn_mfma_f32_16x16x32_f16((af), (bf), (cf), 0, 0, 0)

// ---------------- packing geometry (all sizes in halves) ----------------
#define WL_PACK_H   (32*8*512)   // 131072 per layer: [nt 0..31][kt 0..7][lane][8]
#define WIN_PACK_H  (8*3*512)    // 12288:            [nt 0..7][kt 0..2][lane][8]
#define WOUT_PACK_H (2*4*512)    // 4096:             [nt 0..1][kt 0..3][lane][8]

#define WS_WL0  0
#define WS_WL1  (WS_WL0 + WL_PACK_H)
#define WS_WIN  (WS_WL1 + WL_PACK_H)
#define WS_WOUT (WS_WIN + WIN_PACK_H)

// ---------------- LDS layout (halves) ----------------
// Abig row: [a 0..127 | h0buf0 128..255 | h0buf1 256..383 | h1buf0 384..511 | h1buf1 512..639] + 8 pad
#define PITCH_A  648
#define PITCH_A0 104     // 96 cols (x|acc) + 8 pad
#define L_WL1  0                               // Wl1 kt0..3: [(nt*4+kt)*512 + lane*8]
#define L_WOUT (L_WL1 + 32*4*512)              // 65536
#define L_ABIG (L_WOUT + WOUT_PACK_H)          // 69632
#define L_A0   (L_ABIG + 16*PITCH_A)           // 80000
#define L_TOT  (L_A0 + 16*PITCH_A0)            // 81664 halves = 163328 B (<= 163840)

__device__ __forceinline__ float sigm(float x) {
    return __builtin_amdgcn_rcpf(1.0f + __builtin_amdgcn_exp2f(-1.442695041f * x));
}
__device__ __forceinline__ float tanh_(float x) {
    // tanh(x) = 1 - 2/(e^{2x}+1); exp2 overflow -> inf -> correct +/-1 saturation
    return 1.0f - 2.0f * __builtin_amdgcn_rcpf(__builtin_amdgcn_exp2f(2.885390082f * x) + 1.0f);
}

// Pack one LSTM layer's [k;rk] (256x512 f32) into fp16 MFMA B-fragments.
// Column permutation: nt = w4*8 + g*2 + hh  ->  src col = g*128 + w4*32 + hh*16 + (lane&15)
__global__ void pack_layer_k(const float* __restrict__ kk, const float* __restrict__ rk,
                             _Float16* __restrict__ dst)
{
    int idx  = blockIdx.x * 256 + threadIdx.x;   // 0..131071
    int j    = idx & 7;
    int lane = (idx >> 3) & 63;
    int fk   = idx >> 9;                          // nt*8 + kt
    int kt   = fk & 7;
    int nt   = fk >> 3;
    int w = nt >> 3, ln = nt & 7, g = ln >> 1, hh = ln & 1;
    int col = g*128 + w*32 + hh*16 + (lane & 15);
    int row = kt*32 + (lane >> 4)*8 + j;
    float v = (row < 128) ? kk[row*512 + col] : rk[(row - 128)*512 + col];
    dst[idx] = (_Float16)v;
}

__global__ void pack_small_k(const float* __restrict__ W_in, const float* __restrict__ W_out,
                             _Float16* __restrict__ dwin, _Float16* __restrict__ dwout)
{
    int idx = blockIdx.x * 256 + threadIdx.x;    // 0..12287
    {
        int j = idx & 7, lane = (idx >> 3) & 63, fk = idx >> 9;  // nt*3 + kt
        int kt = fk % 3, nt = fk / 3;
        int col = nt*16 + (lane & 15);
        int row = kt*32 + (lane >> 4)*8 + j;
        dwin[idx] = (_Float16)W_in[row*128 + col];
    }
    if (idx < WOUT_PACK_H) {
        int j = idx & 7, lane = (idx >> 3) & 63, fk = idx >> 9;  // nt*4 + kt
        int kt = fk & 3, nt = fk >> 2;
        int col = nt*16 + (lane & 15);
        int row = kt*32 + (lane >> 4)*8 + j;
        dwout[idx] = (_Float16)W_out[row*32 + col];
    }
}

// 8 waves / block (2 per SIMD). Wave W = (w4, hh): owns hidden cols
// w4*32 + hh*16 + [0,16) of every gate, for both LSTM layers, plus a-cols
// [16W, 16W+16) of GEMM1. Waves 0,1 additionally own GEMM4 + acc.
__global__ __launch_bounds__(512, 2)
void acclstm_main(const float* __restrict__ xin,
                  const _Float16* __restrict__ wl0p, const _Float16* __restrict__ wl1p,
                  const _Float16* __restrict__ winp, const _Float16* __restrict__ woutp,
                  const float* __restrict__ bin, const float* __restrict__ bb0,
                  const float* __restrict__ bb1, const float* __restrict__ bout,
                  float* __restrict__ out)
{
    __shared__ __align__(16) _Float16 lds[L_TOT];
    const int tid  = threadIdx.x;
    const int W    = tid >> 6;        // wave 0..7
    const int lane = tid & 63;
    const int w4   = W & 3;
    const int hh   = W >> 2;
    const int l15  = lane & 15;
    const int lg   = lane >> 4;
    const int b0   = blockIdx.x << 4; // 16 batch rows per block
    const int colw = w4*32 + hh*16 + l15;   // owned hidden col (0..127)

    // ---- prologue: fill LDS (Wl1 kt0..3, W_out, zero Abig+A0) ----
    for (int i = tid; i < 8192; i += 512) {
        int h   = i << 3;
        int nt  = h >> 11;           // 2048 halves per nt in dst (kt0..3)
        int rem = h & 2047;          // kt*512 + lane*8 + j  (kt<4)
        *reinterpret_cast<uint4*>(&lds[L_WL1 + h]) =
            *reinterpret_cast<const uint4*>(&wl1p[nt*4096 + rem]);
    }
    if (tid < 512)
        *reinterpret_cast<uint4*>(&lds[L_WOUT + (tid << 3)]) =
            *reinterpret_cast<const uint4*>(&woutp[tid << 3]);
    {
        uint4 z; z.x = z.y = z.z = z.w = 0u;
        for (int i = tid; i < 1504; i += 512)      // Abig(10368) + A0(1664) = 12032 halves
            *reinterpret_cast<uint4*>(&lds[L_ABIG + (i << 3)]) = z;
    }

    // ---- persistent register weight fragments (per wave: its (w4,hh) slice) ----
    half8 wl0r[4][8];   // [gate][kt]    layer0 full K
    half8 wl1r[4][4];   // [gate][kt-4]  layer1 recurrent half
    #pragma unroll
    for (int g = 0; g < 4; ++g) {
        const int nt = w4*8 + g*2 + hh;
        #pragma unroll
        for (int kt = 0; kt < 8; ++kt)
            wl0r[g][kt] = *reinterpret_cast<const half8*>(&wl0p[(nt*8 + kt)*512 + lane*8]);
        #pragma unroll
        for (int kt = 0; kt < 4; ++kt)
            wl1r[g][kt] = *reinterpret_cast<const half8*>(&wl1p[(nt*8 + 4 + kt)*512 + lane*8]);
    }
    half8 winr[3];
    #pragma unroll
    for (int kt = 0; kt < 3; ++kt)
        winr[kt] = *reinterpret_cast<const half8*>(&winp[(W*3 + kt)*512 + lane*8]);

    float bb0v[4], bb1v[4];
    #pragma unroll
    for (int g = 0; g < 4; ++g) {
        bb0v[g] = bb0[g*128 + colw];
        bb1v[g] = bb1[g*128 + colw];
    }
    const float binv  = bin[W*16 + l15];
    const float boutv = (W < 2) ? bout[W*16 + l15] : 0.0f;

    f32x4 c0 = {0.f,0.f,0.f,0.f}, c1 = {0.f,0.f,0.f,0.f}, accv = {0.f,0.f,0.f,0.f};

    const int xrow = tid >> 5, xc2 = (tid & 31) << 1;
    float2 xr = *reinterpret_cast<const float2*>(&xin[(size_t)(b0 + xrow)*16384 + xc2]);

    __syncthreads();

    int p = 0;  // h-state buffer holding h_{t-1}
    #pragma unroll 1
    for (int t = 0; t < 256; ++t) {
        const int pn = p ^ 1;
        // ---- phase A: stage A0 = [x_t | acc] as fp16; prefetch x_{t+1} ----
        {
            half2v xh = { (_Float16)xr.x, (_Float16)xr.y };
            *reinterpret_cast<half2v*>(&lds[L_A0 + xrow*PITCH_A0 + xc2]) = xh;
        }
        if (W < 2) {
            #pragma unroll
            for (int r = 0; r < 4; ++r)
                lds[L_A0 + (lg*4 + r)*PITCH_A0 + 64 + W*16 + l15] = (_Float16)accv[r];
        }
        {
            const int tn = (t < 255) ? (t + 1) : t;
            xr = *reinterpret_cast<const float2*>(&xin[(size_t)(b0 + xrow)*16384 + tn*64 + xc2]);
        }
        __syncthreads();  // B1: A0 ready

        // ---- GEMM1: a-cols [16W,16W+16) = A0 @ W_in + b_in ----
        {
            f32x4 aa = {0.f,0.f,0.f,0.f};
            #pragma unroll
            for (int kt = 0; kt < 3; ++kt) {
                half8 af = *reinterpret_cast<const half8*>(&lds[L_A0 + l15*PITCH_A0 + kt*32 + lg*8]);
                aa = MFMA16(af, winr[kt], aa);
            }
            #pragma unroll
            for (int r = 0; r < 4; ++r)
                lds[L_ABIG + (lg*4 + r)*PITCH_A + W*16 + l15] = (_Float16)(aa[r] + binv);
        }
        __syncthreads();  // B2: a ready

        // ---- LSTM layer 0: z = [a | h0buf[p]] @ Wl0 -> h0buf[pn] ----
        {
            f32x4 z0 = {0.f,0.f,0.f,0.f}, z1 = {0.f,0.f,0.f,0.f};
            f32x4 z2 = {0.f,0.f,0.f,0.f}, z3 = {0.f,0.f,0.f,0.f};
            #pragma unroll
            for (int kt = 0; kt < 8; ++kt) {
                const int cbase = (kt < 4) ? (kt*32) : (128 + p*128 + (kt-4)*32);
                half8 af = *reinterpret_cast<const half8*>(&lds[L_ABIG + l15*PITCH_A + cbase + lg*8]);
                z0 = MFMA16(af, wl0r[0][kt], z0);
                z1 = MFMA16(af, wl0r[1][kt], z1);
                z2 = MFMA16(af, wl0r[2][kt], z2);
                z3 = MFMA16(af, wl0r[3][kt], z3);
            }
            #pragma unroll
            for (int r = 0; r < 4; ++r) {
                float iv = sigm (z0[r] + bb0v[0]);
                float fv = sigm (z1[r] + bb0v[1]);
                float gv = tanh_(z2[r] + bb0v[2]);
                float ov = sigm (z3[r] + bb0v[3]);
                float cn = fv * c0[r] + iv * gv;
                c0[r] = cn;
                lds[L_ABIG + (lg*4 + r)*PITCH_A + 128 + pn*128 + colw] = (_Float16)(ov * tanh_(cn));
            }
        }
        __syncthreads();  // B3: h0_new ready

        // ---- LSTM layer 1: z = [h0buf[pn] | h1buf[p]] @ Wl1 -> h1buf[pn] ----
        {
            f32x4 z0 = {0.f,0.f,0.f,0.f}, z1 = {0.f,0.f,0.f,0.f};
            f32x4 z2 = {0.f,0.f,0.f,0.f}, z3 = {0.f,0.f,0.f,0.f};
            #pragma unroll
            for (int kt = 0; kt < 4; ++kt) {
                half8 af = *reinterpret_cast<const half8*>(&lds[L_ABIG + l15*PITCH_A + 128 + pn*128 + kt*32 + lg*8]);
                const int nb = (w4*8 + hh)*4 + kt;  // nt*4+kt with g folded below
                z0 = MFMA16(af, *reinterpret_cast<const half8*>(&lds[L_WL1 + (nb + 0*8)*512 + lane*8]), z0);
                z1 = MFMA16(af, *reinterpret_cast<const half8*>(&lds[L_WL1 + (nb + 1*8)*512 + lane*8]), z1);
                z2 = MFMA16(af, *reinterpret_cast<const half8*>(&lds[L_WL1 + (nb + 2*8)*512 + lane*8]), z2);
                z3 = MFMA16(af, *reinterpret_cast<const half8*>(&lds[L_WL1 + (nb + 3*8)*512 + lane*8]), z3);
            }
            #pragma unroll
            for (int kt = 0; kt < 4; ++kt) {
                half8 af = *reinterpret_cast<const half8*>(&lds[L_ABIG + l15*PITCH_A + 384 + p*128 + kt*32 + lg*8]);
                z0 = MFMA16(af, wl1r[0][kt], z0);
                z1 = MFMA16(af, wl1r[1][kt], z1);
                z2 = MFMA16(af, wl1r[2][kt], z2);
                z3 = MFMA16(af, wl1r[3][kt], z3);
            }
            #pragma unroll
            for (int r = 0; r < 4; ++r) {
                float iv = sigm (z0[r] + bb1v[0]);
                float fv = sigm (z1[r] + bb1v[1]);
                float gv = tanh_(z2[r] + bb1v[2]);
                float ov = sigm (z3[r] + bb1v[3]);
                float cn = fv * c1[r] + iv * gv;
                c1[r] = cn;
                lds[L_ABIG + (lg*4 + r)*PITCH_A + 384 + pn*128 + colw] = (_Float16)(ov * tanh_(cn));
            }
        }
        __syncthreads();  // B4: h1_new ready

        // ---- GEMM4 (waves 0,1): res = h1buf[pn] @ W_out + b_out; out; acc += ----
        if (W < 2) {
            f32x4 rr = {0.f,0.f,0.f,0.f};
            #pragma unroll
            for (int kt = 0; kt < 4; ++kt) {
                half8 af = *reinterpret_cast<const half8*>(&lds[L_ABIG + l15*PITCH_A + 384 + pn*128 + kt*32 + lg*8]);
                half8 wf = *reinterpret_cast<const half8*>(&lds[L_WOUT + (W*4 + kt)*512 + lane*8]);
                rr = MFMA16(af, wf, rr);
            }
            #pragma unroll
            for (int r = 0; r < 4; ++r) {
                float res = rr[r] + boutv;
                out[(size_t)(b0 + lg*4 + r)*8192 + t*32 + W*16 + l15] = res;
                accv[r] += res;
            }
        }
        p = pn;
        // next B1 orders GEMM4/h1 reads vs next-step A0/a writes.
    }
}

extern "C" void kernel_launch(void* const* d_in, const int* in_sizes, int n_in,
                              void* d_out, int out_size, void* d_ws, size_t ws_size,
                              hipStream_t stream) {
    (void)in_sizes; (void)n_in; (void)out_size; (void)ws_size;
    const float* x     = (const float*)d_in[0];
    const float* W_in  = (const float*)d_in[1];
    const float* b_in  = (const float*)d_in[2];
    const float* k0    = (const float*)d_in[3];
    const float* rk0   = (const float*)d_in[4];
    const float* bb0   = (const float*)d_in[5];
    const float* k1    = (const float*)d_in[6];
    const float* rk1   = (const float*)d_in[7];
    const float* bb1   = (const float*)d_in[8];
    const float* W_out = (const float*)d_in[9];
    const float* b_out = (const float*)d_in[10];
    float* out = (float*)d_out;

    _Float16* ws    = (_Float16*)d_ws;
    _Float16* wl0p  = ws + WS_WL0;
    _Float16* wl1p  = ws + WS_WL1;
    _Float16* winp  = ws + WS_WIN;
    _Float16* woutp = ws + WS_WOUT;

    pack_layer_k<<<512, 256, 0, stream>>>(k0, rk0, wl0p);
    pack_layer_k<<<512, 256, 0, stream>>>(k1, rk1, wl1p);
    pack_small_k<<<48, 256, 0, stream>>>(W_in, W_out, winp, woutp);
    acclstm_main<<<256, 512, 0, stream>>>(x, wl0p, wl1p, winp, woutp,
                                          b_in, bb0, bb1, b_out, out);
}

// Round 3
// 780.548 us; speedup vs baseline: 1.8438x; 1.8315x over previous
//
#include <hip/hip_runtime.h>
#include <hip/hip_fp16.h>

typedef _Float16 half8  __attribute__((ext_vector_type(8)));
typedef _Float16 half2v __attribute__((ext_vector_type(2)));
typedef float    f32x4  __attribute__((ext_vector_type(4)));

#define MFMA16(af, bf, cf) __builtin_amdgcn_mfma_f32_16x16x32_f16((af), (bf), (cf), 0, 0, 0)

// ---------------- workspace layout (halves) ----------------
#define WS_WL1  0                         // layer1 [k1;rk1] packed: [nt0..31][kt0..7][lane][8] = 131072
#define WS_RK0  131072                    // rk0 packed: [nt0..31][kt0..3][lane][8] = 65536
#define WS_W0   (131072 + 65536)          // W0' = W_in@k0 packed: [nt0..31][kt0..2][lane][8] = 49152
#define WS_WOUT (WS_W0 + 49152)           // W_out packed: [nt0..1][kt0..3][lane][8] = 4096
#define WS_B0   (WS_WOUT + 4096)          // float b0'[512] lives here (as float*, 2 halves each)

// ---------------- LDS layout (halves) ----------------
// Hot per-step regions low (ds offset immediates), big weights high.
#define PA0 104                            // 96 cols (x|acc) + 8 pad
#define PH  136                            // 128 cols + 8 pad
#define L_A0   0                           // 2 x [16][104] = 3328
#define L_H0   3328                        // 2 x [16][136] = 4352
#define L_H1   (L_H0 + 4352)               // 7680: 2 x [16][136]
#define L_WOUT (L_H1 + 4352)               // 12032: [2nt][4kt][512] = 4096
#define L_K1   (L_WOUT + 4096)             // 16128: k1 kt0..3: [nt][kt][512] = 65536
#define L_TOT  (L_K1 + 65536)              // 81664 halves = 163328 B (<= 163840)

__device__ __forceinline__ float sigm(float x) {
    return __builtin_amdgcn_rcpf(1.0f + __builtin_amdgcn_exp2f(-1.442695041f * x));
}
__device__ __forceinline__ float tanh_(float x) {
    return 1.0f - 2.0f * __builtin_amdgcn_rcpf(__builtin_amdgcn_exp2f(2.885390082f * x) + 1.0f);
}
// raw barrier: drain LDS only; global loads/stores stay in flight.
__device__ __forceinline__ void bar() {
    asm volatile("s_waitcnt lgkmcnt(0)" ::: "memory");
    __builtin_amdgcn_s_barrier();
    asm volatile("" ::: "memory");
}

// ---- pack kernels (run once per launch; all outputs deterministic) ----

// [k;rk] (2x 128x512) -> fp16 frags [nt][kt0..7][lane][8]; nt = w4*8+g*2+hh
__global__ void pack_layer_k(const float* __restrict__ kk, const float* __restrict__ rk,
                             _Float16* __restrict__ dst)
{
    int idx  = blockIdx.x * 256 + threadIdx.x;   // < 131072
    int j    = idx & 7;
    int lane = (idx >> 3) & 63;
    int fk   = idx >> 9;                          // nt*8 + kt
    int kt   = fk & 7;
    int nt   = fk >> 3;
    int w = nt >> 3, ln = nt & 7, g = ln >> 1, hh = ln & 1;
    int col = g*128 + w*32 + hh*16 + (lane & 15);
    int row = kt*32 + (lane >> 4)*8 + j;
    float v = (row < 128) ? kk[row*512 + col] : rk[(row - 128)*512 + col];
    dst[idx] = (_Float16)v;
}

// rk0 (128x512) -> [nt][kt0..3][lane][8]
__global__ void pack_rk(const float* __restrict__ rk, _Float16* __restrict__ dst)
{
    int idx = blockIdx.x * 256 + threadIdx.x;    // < 65536
    int j = idx & 7, lane = (idx >> 3) & 63, fk = idx >> 9;  // nt*4+kt
    int kt = fk & 3, nt = fk >> 2;
    int w = nt >> 3, ln = nt & 7, g = ln >> 1, hh = ln & 1;
    int col = g*128 + w*32 + hh*16 + (lane & 15);
    int row = kt*32 + (lane >> 4)*8 + j;          // < 128
    dst[idx] = (_Float16)rk[row*512 + col];
}

// W0' = W_in(96x128) @ k0(128x512) -> [nt][kt0..2][lane][8]
__global__ void pack_w0(const float* __restrict__ W_in, const float* __restrict__ k0,
                        _Float16* __restrict__ dst)
{
    int idx = blockIdx.x * 256 + threadIdx.x;    // < 49152
    int j = idx & 7, lane = (idx >> 3) & 63, fk = idx >> 9;  // nt*3+kt
    int kt = fk % 3, nt = fk / 3;
    int w = nt >> 3, ln = nt & 7, g = ln >> 1, hh = ln & 1;
    int col = g*128 + w*32 + hh*16 + (lane & 15);
    int row = kt*32 + (lane >> 4)*8 + j;          // < 96
    float s = 0.f;
    #pragma unroll 4
    for (int k = 0; k < 128; ++k) s += W_in[row*128 + k] * k0[k*512 + col];
    dst[idx] = (_Float16)s;
}

// b0' = b_in @ k0 + bb0  (f32, 512)
__global__ void pack_b0(const float* __restrict__ b_in, const float* __restrict__ k0,
                        const float* __restrict__ bb0, float* __restrict__ b0p)
{
    int col = blockIdx.x * 256 + threadIdx.x;    // < 512
    float s = bb0[col];
    #pragma unroll 4
    for (int k = 0; k < 128; ++k) s += b_in[k] * k0[k*512 + col];
    b0p[col] = s;
}

// W_out (128x32) -> [nt0..1][kt0..3][lane][8]
__global__ void pack_wout(const float* __restrict__ W_out, _Float16* __restrict__ dst)
{
    int idx = blockIdx.x * 256 + threadIdx.x;    // < 4096
    int j = idx & 7, lane = (idx >> 3) & 63, fk = idx >> 9;  // nt*4+kt
    int kt = fk & 3, nt = fk >> 2;
    int col = nt*16 + (lane & 15);
    int row = kt*32 + (lane >> 4)*8 + j;
    dst[idx] = (_Float16)W_out[row*32 + col];
}

// 8 waves (2/SIMD). Wave W=(w4,hh) owns hidden cols w4*32+hh*16+[0,16) of every
// gate for both layers. 3 raw barriers/step; x & out traffic never drained.
__global__ __launch_bounds__(512, 2)
void acclstm_main(const float* __restrict__ xin,
                  const _Float16* __restrict__ wl1p, const _Float16* __restrict__ rk0p,
                  const _Float16* __restrict__ w0p,  const _Float16* __restrict__ woutp,
                  const float* __restrict__ b0p, const float* __restrict__ bb1,
                  const float* __restrict__ bout, float* __restrict__ out)
{
    __shared__ __align__(16) _Float16 lds[L_TOT];
    const int tid  = threadIdx.x;
    const int W    = tid >> 6;        // wave 0..7
    const int lane = tid & 63;
    const int w4   = W & 3;
    const int hh   = W >> 2;
    const int l15  = lane & 15;
    const int lg   = lane >> 4;
    const int b0   = blockIdx.x << 4; // 16 batch rows
    const int colw = w4*32 + hh*16 + l15;

    // ---- LDS fills ----
    for (int i = tid; i < 8192; i += 512) {       // k1 = kt0..3 of wl1p
        int h = i << 3, nt = h >> 11, rem = h & 2047;
        *reinterpret_cast<uint4*>(&lds[L_K1 + h]) =
            *reinterpret_cast<const uint4*>(&wl1p[nt*4096 + rem]);
    }
    *reinterpret_cast<uint4*>(&lds[L_WOUT + (tid << 3)]) =
        *reinterpret_cast<const uint4*>(&woutp[tid << 3]);
    {
        uint4 z; z.x = z.y = z.z = z.w = 0u;
        for (int i = tid; i < 1504; i += 512)     // zero A0/H0/H1 (both parities)
            *reinterpret_cast<uint4*>(&lds[i << 3]) = z;
    }

    // ---- persistent weight fragments ----
    half8 w0r[4][3], rk0r[4][4], rk1r[4][4];
    #pragma unroll
    for (int g = 0; g < 4; ++g) {
        const int nt = w4*8 + g*2 + hh;
        #pragma unroll
        for (int kt = 0; kt < 3; ++kt)
            w0r[g][kt] = *reinterpret_cast<const half8*>(&w0p[(nt*3 + kt)*512 + lane*8]);
        #pragma unroll
        for (int kt = 0; kt < 4; ++kt)
            rk0r[g][kt] = *reinterpret_cast<const half8*>(&rk0p[(nt*4 + kt)*512 + lane*8]);
        #pragma unroll
        for (int kt = 0; kt < 4; ++kt)
            rk1r[g][kt] = *reinterpret_cast<const half8*>(&wl1p[(nt*8 + 4 + kt)*512 + lane*8]);
    }
    float b0v[4], b1v[4];
    #pragma unroll
    for (int g = 0; g < 4; ++g) {
        b0v[g] = b0p[g*128 + colw];
        b1v[g] = bb1[g*128 + colw];
    }
    const float boutv = (W < 2) ? bout[W*16 + l15] : 0.0f;

    f32x4 c0 = {0.f,0.f,0.f,0.f}, c1 = {0.f,0.f,0.f,0.f}, accv = {0.f,0.f,0.f,0.f};

    const int xrow = tid >> 5, xc2 = (tid & 31) << 1;
    __syncthreads();
    // x0 -> A0buf[0]; xr = x1
    float2 xr = *reinterpret_cast<const float2*>(&xin[(size_t)(b0 + xrow)*16384 + xc2]);
    {
        half2v xh = { (_Float16)xr.x, (_Float16)xr.y };
        *reinterpret_cast<half2v*>(&lds[L_A0 + xrow*PA0 + xc2]) = xh;
    }
    xr = *reinterpret_cast<const float2*>(&xin[(size_t)(b0 + xrow)*16384 + 64 + xc2]);
    __syncthreads();

    auto step = [&](auto PARc, int t) {
        constexpr int PAR = decltype(PARc)::value;
        constexpr int A0r = L_A0 + PAR*1664,       A0w = L_A0 + (PAR^1)*1664;
        constexpr int H0r = L_H0 + PAR*2176,       H0w = L_H0 + (PAR^1)*2176;
        constexpr int H1r = L_H1 + PAR*2176,       H1w = L_H1 + (PAR^1)*2176;

        // ---- seg1: z0 = [x|acc]@W0' + h0_prev@rk0 -> h0 ----
        {
            f32x4 z0={0.f,0.f,0.f,0.f}, z1={0.f,0.f,0.f,0.f};
            f32x4 z2={0.f,0.f,0.f,0.f}, z3={0.f,0.f,0.f,0.f};
            #pragma unroll
            for (int kt = 0; kt < 3; ++kt) {
                half8 af = *reinterpret_cast<const half8*>(&lds[A0r + l15*PA0 + kt*32 + lg*8]);
                z0 = MFMA16(af, w0r[0][kt], z0);
                z1 = MFMA16(af, w0r[1][kt], z1);
                z2 = MFMA16(af, w0r[2][kt], z2);
                z3 = MFMA16(af, w0r[3][kt], z3);
            }
            #pragma unroll
            for (int kt = 0; kt < 4; ++kt) {
                half8 af = *reinterpret_cast<const half8*>(&lds[H0r + l15*PH + kt*32 + lg*8]);
                z0 = MFMA16(af, rk0r[0][kt], z0);
                z1 = MFMA16(af, rk0r[1][kt], z1);
                z2 = MFMA16(af, rk0r[2][kt], z2);
                z3 = MFMA16(af, rk0r[3][kt], z3);
            }
            #pragma unroll
            for (int r = 0; r < 4; ++r) {
                float iv = sigm (z0[r] + b0v[0]);
                float fv = sigm (z1[r] + b0v[1]);
                float gv = tanh_(z2[r] + b0v[2]);
                float ov = sigm (z3[r] + b0v[3]);
                float cn = fv * c0[r] + iv * gv;
                c0[r] = cn;
                lds[H0w + (lg*4 + r)*PH + colw] = (_Float16)(ov * tanh_(cn));
            }
        }
        bar();  // h0 ready

        // ---- seg2: z1 = h0@k1(LDS) + h1_prev@rk1 -> h1 ----
        {
            f32x4 z0={0.f,0.f,0.f,0.f}, z1={0.f,0.f,0.f,0.f};
            f32x4 z2={0.f,0.f,0.f,0.f}, z3={0.f,0.f,0.f,0.f};
            #pragma unroll
            for (int kt = 0; kt < 4; ++kt) {
                half8 af = *reinterpret_cast<const half8*>(&lds[H0w + l15*PH + kt*32 + lg*8]);
                z0 = MFMA16(af, *reinterpret_cast<const half8*>(&lds[L_K1 + ((w4*8 + 0 + hh)*4 + kt)*512 + lane*8]), z0);
                z1 = MFMA16(af, *reinterpret_cast<const half8*>(&lds[L_K1 + ((w4*8 + 2 + hh)*4 + kt)*512 + lane*8]), z1);
                z2 = MFMA16(af, *reinterpret_cast<const half8*>(&lds[L_K1 + ((w4*8 + 4 + hh)*4 + kt)*512 + lane*8]), z2);
                z3 = MFMA16(af, *reinterpret_cast<const half8*>(&lds[L_K1 + ((w4*8 + 6 + hh)*4 + kt)*512 + lane*8]), z3);
            }
            #pragma unroll
            for (int kt = 0; kt < 4; ++kt) {
                half8 af = *reinterpret_cast<const half8*>(&lds[H1r + l15*PH + kt*32 + lg*8]);
                z0 = MFMA16(af, rk1r[0][kt], z0);
                z1 = MFMA16(af, rk1r[1][kt], z1);
                z2 = MFMA16(af, rk1r[2][kt], z2);
                z3 = MFMA16(af, rk1r[3][kt], z3);
            }
            #pragma unroll
            for (int r = 0; r < 4; ++r) {
                float iv = sigm (z0[r] + b1v[0]);
                float fv = sigm (z1[r] + b1v[1]);
                float gv = tanh_(z2[r] + b1v[2]);
                float ov = sigm (z3[r] + b1v[3]);
                float cn = fv * c1[r] + iv * gv;
                c1[r] = cn;
                lds[H1w + (lg*4 + r)*PH + colw] = (_Float16)(ov * tanh_(cn));
            }
        }
        bar();  // h1 ready

        // ---- seg3: out = h1@Wout + bout; acc += res -> A0_next; stage x ----
        if (W < 2) {
            f32x4 rr = {0.f,0.f,0.f,0.f};
            #pragma unroll
            for (int kt = 0; kt < 4; ++kt) {
                half8 af = *reinterpret_cast<const half8*>(&lds[H1w + l15*PH + kt*32 + lg*8]);
                half8 wf = *reinterpret_cast<const half8*>(&lds[L_WOUT + (W*4 + kt)*512 + lane*8]);
                rr = MFMA16(af, wf, rr);
            }
            #pragma unroll
            for (int r = 0; r < 4; ++r) {
                float res = rr[r] + boutv;
                out[(size_t)(b0 + lg*4 + r)*8192 + t*32 + W*16 + l15] = res;
                accv[r] += res;
                lds[A0w + (lg*4 + r)*PA0 + 64 + W*16 + l15] = (_Float16)accv[r];
            }
        }
        {
            half2v xh = { (_Float16)xr.x, (_Float16)xr.y };
            *reinterpret_cast<half2v*>(&lds[A0w + xrow*PA0 + xc2]) = xh;
            int tn = t + 2; if (tn > 255) tn = 255;
            xr = *reinterpret_cast<const float2*>(&xin[(size_t)(b0 + xrow)*16384 + tn*64 + xc2]);
        }
        bar();  // A0_next ready
    };

    #pragma unroll 1
    for (int t = 0; t < 256; t += 2) {
        step(std::integral_constant<int,0>{}, t);
        step(std::integral_constant<int,1>{}, t + 1);
    }
}

extern "C" void kernel_launch(void* const* d_in, const int* in_sizes, int n_in,
                              void* d_out, int out_size, void* d_ws, size_t ws_size,
                              hipStream_t stream) {
    (void)in_sizes; (void)n_in; (void)out_size; (void)ws_size;
    const float* x     = (const float*)d_in[0];
    const float* W_in  = (const float*)d_in[1];
    const float* b_in  = (const float*)d_in[2];
    const float* k0    = (const float*)d_in[3];
    const float* rk0   = (const float*)d_in[4];
    const float* bb0   = (const float*)d_in[5];
    const float* k1    = (const float*)d_in[6];
    const float* rk1   = (const float*)d_in[7];
    const float* bb1   = (const float*)d_in[8];
    const float* W_out = (const float*)d_in[9];
    const float* b_out = (const float*)d_in[10];
    float* out = (float*)d_out;

    _Float16* ws    = (_Float16*)d_ws;
    _Float16* wl1p  = ws + WS_WL1;
    _Float16* rk0p  = ws + WS_RK0;
    _Float16* w0p   = ws + WS_W0;
    _Float16* woutp = ws + WS_WOUT;
    float*    b0p   = (float*)(ws + WS_B0);

    pack_layer_k<<<512, 256, 0, stream>>>(k1, rk1, wl1p);
    pack_rk     <<<256, 256, 0, stream>>>(rk0, rk0p);
    pack_w0     <<<192, 256, 0, stream>>>(W_in, k0, w0p);
    pack_b0     <<<2,   256, 0, stream>>>(b_in, k0, bb0, b0p);
    pack_wout   <<<16,  256, 0, stream>>>(W_out, woutp);
    acclstm_main<<<256, 512, 0, stream>>>(x, wl1p, rk0p, w0p, woutp,
                                          b0p, bb1, b_out, out);
}